// Round 7
// baseline (141.988 us; speedup 1.0000x reference)
//
#include <hip/hip_runtime.h>
#include <hip/hip_bf16.h>

#define C_   512
#define HS   128
#define NN   10368   // 18*24*24 ; 324 k-steps of 32

typedef __bf16 bf16x8 __attribute__((ext_vector_type(8)));
typedef float  f32x4  __attribute__((ext_vector_type(4)));

__device__ __forceinline__ bf16x8 load_f32x8_as_bf16(const float* __restrict__ p) {
    float4 v0 = *(const float4*)p;
    float4 v1 = *(const float4*)(p + 4);
    bf16x8 o;
    o[0] = (__bf16)v0.x; o[1] = (__bf16)v0.y; o[2] = (__bf16)v0.z; o[3] = (__bf16)v0.w;
    o[4] = (__bf16)v1.x; o[5] = (__bf16)v1.y; o[6] = (__bf16)v1.z; o[7] = (__bf16)v1.w;
    return o;
}

// ---------------------------------------------------------------------------
// K1: blocks [0,1296): 64x64 tile: read feat fp32 [C][N] once, write BOTH
//       xb  bf16 [C][N]  (coalesced, n-contiguous)  -> K3's A operand
//       xbT bf16 [N][C]  (via LDS stride-65)        -> K2's operand
//     blocks [1296,1312): zero Mtf (fp32 [C][HS]) for K3's atomics.
// ---------------------------------------------------------------------------
__global__ void k_transpose(const float* __restrict__ x, __bf16* __restrict__ xb,
                            __bf16* __restrict__ xbT, float* __restrict__ Mtf) {
    const int b = blockIdx.x;
    const int t = threadIdx.x;
    if (b < 1296) {
        __shared__ float tile[64][65];
        const int c0 = (b & 7) * 64, n0 = (b >> 3) * 64;
        const int tr = t >> 6, tn = t & 63;
        #pragma unroll
        for (int i = 0; i < 16; i++) {
            int c = tr + i * 4;
            float v = x[(size_t)(c0 + c) * NN + n0 + tn];
            xb[(size_t)(c0 + c) * NN + n0 + tn] = (__bf16)v;
            tile[c][tn] = v;
        }
        __syncthreads();
        #pragma unroll
        for (int i = 0; i < 16; i++) {
            int n = tr + i * 4;
            xbT[(size_t)(n0 + n) * C_ + c0 + tn] = (__bf16)tile[tn][n];
        }
    } else {
        const int j = b - 1296;                 // 0..15, 4096 floats each
        f32x4 z = {0.f, 0.f, 0.f, 0.f};
        float* p = Mtf + j * 4096 + t * 16;
        *(f32x4*)(p)      = z;
        *(f32x4*)(p + 4)  = z;
        *(f32x4*)(p + 8)  = z;
        *(f32x4*)(p + 12) = z;
    }
}

// ---------------------------------------------------------------------------
// K2 (fused G1+G2): 1296 waves. Weights read fp32 + in-register cvt.
//   waves [0,648):   fj[h][n]   = sum_c Wj[h][c]*x[c][n] + bj[h]
//   waves [648,1296) finm[n][h] = sum_c x[c][n]*Wi[h][c] + bi[h]
// ---------------------------------------------------------------------------
__global__ void k_gemm12(const __bf16* __restrict__ xbT,
                         const float* __restrict__ Wi, const float* __restrict__ Wj,
                         const float* __restrict__ bi, const float* __restrict__ bj,
                         __bf16* __restrict__ fj, __bf16* __restrict__ finm) {
    const int w    = blockIdx.x * 4 + (threadIdx.x >> 6);
    const int lane = threadIdx.x & 63;
    const int l16  = lane & 15;
    const int q    = lane >> 4;
    if (w < 648) {
        const int h0 = (w & 3) * 32, n0 = (w >> 2) * 64;
        f32x4 acc[2][4] = {};
        for (int k = 0; k < 512; k += 32) {
            bf16x8 a[2], b[4];
            #pragma unroll
            for (int i = 0; i < 2; i++)
                a[i] = load_f32x8_as_bf16(Wj + (h0 + 16 * i + l16) * 512 + k + q * 8);
            #pragma unroll
            for (int tt = 0; tt < 4; tt++)
                b[tt] = *(const bf16x8*)(xbT + (size_t)(n0 + 16 * tt + l16) * 512 + k + q * 8);
            #pragma unroll
            for (int i = 0; i < 2; i++)
                #pragma unroll
                for (int tt = 0; tt < 4; tt++)
                    acc[i][tt] = __builtin_amdgcn_mfma_f32_16x16x32_bf16(a[i], b[tt], acc[i][tt], 0, 0, 0);
        }
        #pragma unroll
        for (int i = 0; i < 2; i++)
            #pragma unroll
            for (int tt = 0; tt < 4; tt++)
                #pragma unroll
                for (int r = 0; r < 4; r++) {
                    int h = h0 + 16 * i + q * 4 + r;
                    int n = n0 + 16 * tt + l16;
                    fj[(size_t)h * NN + n] = (__bf16)(acc[i][tt][r] + bj[h]);
                }
    } else {
        const int w2 = w - 648;
        const int n0 = (w2 >> 2) * 64, h0 = (w2 & 3) * 32;
        f32x4 acc[4][2] = {};
        for (int k = 0; k < 512; k += 32) {
            bf16x8 a[4], b[2];
            #pragma unroll
            for (int i = 0; i < 4; i++)
                a[i] = *(const bf16x8*)(xbT + (size_t)(n0 + 16 * i + l16) * 512 + k + q * 8);
            #pragma unroll
            for (int tt = 0; tt < 2; tt++)
                b[tt] = load_f32x8_as_bf16(Wi + (h0 + 16 * tt + l16) * 512 + k + q * 8);
            #pragma unroll
            for (int i = 0; i < 4; i++)
                #pragma unroll
                for (int tt = 0; tt < 2; tt++)
                    acc[i][tt] = __builtin_amdgcn_mfma_f32_16x16x32_bf16(a[i], b[tt], acc[i][tt], 0, 0, 0);
        }
        #pragma unroll
        for (int i = 0; i < 4; i++)
            #pragma unroll
            for (int tt = 0; tt < 2; tt++)
                #pragma unroll
                for (int r = 0; r < 4; r++) {
                    int n = n0 + 16 * i + q * 4 + r;
                    int h = h0 + 16 * tt + l16;
                    finm[(size_t)n * HS + h] = (__bf16)(acc[i][tt][r] + bi[h]);
                }
    }
}

// ---------------------------------------------------------------------------
// K3 (G3): Mtf[c][h] += sum_n xb[c][n] * fj[h][n]   (fp32 atomics)
//   512 blocks x 256 thr (2 blocks/CU, 8 waves/CU — full chip):
//   64 tiles (32c x 32h) x 8 chunk-groups; the 4 waves of a block take 4
//   adjacent K-chunks (~10 ksteps each), LDS-reduce, 8-contender atomicAdd.
//   A reads bf16 xb directly (half the fetch of fp32 feat, no cvt).
// ---------------------------------------------------------------------------
__global__ void k_gemm3(const __bf16* __restrict__ xb, const __bf16* __restrict__ fj,
                        float* __restrict__ Mtf) {
    __shared__ float red[4][64][17];
    const int b    = blockIdx.x;          // 0..511
    const int t    = threadIdx.x;         // 0..255
    const int v    = t >> 6;              // wave 0..3
    const int lane = t & 63;
    const int l16  = lane & 15;
    const int q    = lane >> 4;
    const int tile = b & 63, g = b >> 6;  // 64 tiles x 8 groups
    const int c0 = (tile >> 2) * 32, h0 = (tile & 3) * 32;
    const int chunk = g * 4 + v;          // 0..31
    const int s0 = (chunk * 324) >> 5;
    const int s1 = ((chunk + 1) * 324) >> 5;
    f32x4 acc[2][2] = {};
    for (int s = s0; s < s1; s++) {
        int k = s * 32;
        bf16x8 a[2], bb[2];
        #pragma unroll
        for (int i = 0; i < 2; i++)
            a[i] = *(const bf16x8*)(xb + (size_t)(c0 + 16 * i + l16) * NN + k + q * 8);
        #pragma unroll
        for (int tt = 0; tt < 2; tt++)
            bb[tt] = *(const bf16x8*)(fj + (size_t)(h0 + 16 * tt + l16) * NN + k + q * 8);
        #pragma unroll
        for (int i = 0; i < 2; i++)
            #pragma unroll
            for (int tt = 0; tt < 2; tt++)
                acc[i][tt] = __builtin_amdgcn_mfma_f32_16x16x32_bf16(a[i], bb[tt], acc[i][tt], 0, 0, 0);
    }
    #pragma unroll
    for (int i = 0; i < 2; i++)
        #pragma unroll
        for (int tt = 0; tt < 2; tt++)
            #pragma unroll
            for (int r = 0; r < 4; r++)
                red[v][lane][i * 8 + tt * 4 + r] = acc[i][tt][r];
    __syncthreads();
    #pragma unroll
    for (int u = 0; u < 4; u++) {
        const int idx = t * 4 + u;        // 0..1023
        const int lane_e = idx >> 4, j = idx & 15;
        float s = red[0][lane_e][j] + red[1][lane_e][j]
                + red[2][lane_e][j] + red[3][lane_e][j];
        const int i = j >> 3, tt = (j >> 2) & 1, r = j & 3;
        const int qe = lane_e >> 4, le = lane_e & 15;
        const int c = c0 + 16 * i + qe * 4 + r;
        const int h = h0 + 16 * tt + le;
        atomicAdd(&Mtf[c * HS + h], s);
    }
}

// ---------------------------------------------------------------------------
// K4 (G4 + scale + residual):
//   out[c][n] = feat[c][n] + (agg/N) * sum_h Mtf[c][h] * finm[n][h]
//   A-fragments from fp32 Mtf (2x f32x4 + cvt), Bt = finm bf16, K=128.
//   Residual read stays fp32 feat (exact).
// ---------------------------------------------------------------------------
__global__ void k_gemm4(const float* __restrict__ Mtf, const __bf16* __restrict__ finm,
                        const float* __restrict__ feat, const float* __restrict__ agg,
                        float* __restrict__ out) {
    const int w    = blockIdx.x * 4 + (threadIdx.x >> 6);   // 0..2591
    const int lane = threadIdx.x & 63;
    const int l16  = lane & 15;
    const int q    = lane >> 4;
    const int c0 = (w & 15) * 32, n0 = (w >> 4) * 64;
    const float scale = agg[0] * (1.0f / (float)NN);
    f32x4 acc[2][4] = {};
    for (int k = 0; k < 128; k += 32) {
        bf16x8 a[2], b[4];
        #pragma unroll
        for (int i = 0; i < 2; i++)
            a[i] = load_f32x8_as_bf16(Mtf + (c0 + 16 * i + l16) * HS + k + q * 8);
        #pragma unroll
        for (int tt = 0; tt < 4; tt++)
            b[tt] = *(const bf16x8*)(finm + (size_t)(n0 + 16 * tt + l16) * HS + k + q * 8);
        #pragma unroll
        for (int i = 0; i < 2; i++)
            #pragma unroll
            for (int tt = 0; tt < 4; tt++)
                acc[i][tt] = __builtin_amdgcn_mfma_f32_16x16x32_bf16(a[i], b[tt], acc[i][tt], 0, 0, 0);
    }
    #pragma unroll
    for (int i = 0; i < 2; i++)
        #pragma unroll
        for (int tt = 0; tt < 4; tt++)
            #pragma unroll
            for (int r = 0; r < 4; r++) {
                int c = c0 + 16 * i + q * 4 + r;
                int n = n0 + 16 * tt + l16;
                size_t idx = (size_t)c * NN + n;
                out[idx] = feat[idx] + scale * acc[i][tt][r];
            }
}

// ---------------------------------------------------------------------------
// Workspace layout (bytes):
//   xb   @ 0          : 10,616,832
//   xbT  @ 10,616,832 : 10,616,832
//   fj   @ 21,233,664 : 2,654,208
//   finm @ 23,887,872 : 2,654,208
//   Mtf  @ 26,542,080 : 262,144       total ~26.8 MB
// ---------------------------------------------------------------------------
extern "C" void kernel_launch(void* const* d_in, const int* in_sizes, int n_in,
                              void* d_out, int out_size, void* d_ws, size_t ws_size,
                              hipStream_t stream) {
    const float* feat = (const float*)d_in[0];
    const float* Wi   = (const float*)d_in[1];
    const float* bi   = (const float*)d_in[2];
    const float* Wj   = (const float*)d_in[3];
    const float* bj   = (const float*)d_in[4];
    const float* agg  = (const float*)d_in[5];
    float* out = (float*)d_out;

    char* ws = (char*)d_ws;
    __bf16* xb   = (__bf16*)(ws);
    __bf16* xbT  = (__bf16*)(ws + 10616832);
    __bf16* fj   = (__bf16*)(ws + 21233664);
    __bf16* finm = (__bf16*)(ws + 23887872);
    float*  Mtf  = (float*) (ws + 26542080);

    k_transpose<<<1312, 256, 0, stream>>>(feat, xb, xbT, Mtf);
    k_gemm12<<<324, 256, 0, stream>>>(xbT, Wi, Wj, bi, bj, fj, finm);
    k_gemm3<<<512, 256, 0, stream>>>(xb, fj, Mtf);
    k_gemm4<<<648, 256, 0, stream>>>(Mtf, finm, feat, agg, out);
}